// Round 5
// baseline (278.174 us; speedup 1.0000x reference)
//
#include <hip/hip_runtime.h>
#include <hip/hip_bf16.h>

// TrittentionCube on MI355X. B=1, P=256, D=512, N=8, H=64. Round 15:
//  - NEW (bigws, bf16 path): proj_mfma + out_mfma replace the scalar-FMA
//    proj_kern<bf16> / gemm_tile<bf16> (each thread was doing 8192 serial
//    v_fma ~16k cyc; s1t_mfma-shaped MFMA loop is ~50x fewer issue slots).
//  - NEW wtrans5/wotrans: 64x64 LDS tile transposes producing k-contiguous
//    weights for MFMA B-frags. WT (2.6 MB) overlaps cpack region (dead until
//    c_kern); WOT (512 KB) written AFTER z_kern into dead Sbuf head.
//  - fp32 path keeps scalar proj_kern<float>/gemm_tile<float> (gated).
//  - tri_attn2 / c_kern / z_kern / zred unchanged from round 14 (verified).
//  - Small-ws fallback path unchanged (round-12 verbatim).

typedef __hip_bfloat16 bf16;
typedef __attribute__((ext_vector_type(8))) short short8;
typedef __attribute__((ext_vector_type(4))) short s16x4;
typedef __attribute__((ext_vector_type(4))) float floatx4;

__device__ __forceinline__ float ldf(const float* p){ return *p; }
__device__ __forceinline__ float ldf(const bf16* p){ return __bfloat162float(*p); }
__device__ __forceinline__ void  stf(float* p, float v){ *p = v; }
__device__ __forceinline__ void  stf(bf16*  p, float v){ *p = __float2bfloat16(v); }

__device__ __forceinline__ floatx4 mfma16(short8 a, short8 b, floatx4 c){
  return __builtin_amdgcn_mfma_f32_16x16x32_bf16(a, b, c, 0, 0, 0);
}
__device__ __forceinline__ short8 ld_g8(const bf16* p){
  return *reinterpret_cast<const short8*>(p);
}
__device__ __forceinline__ short bfs(float x){
  bf16 v = __float2bfloat16(x);
  return *reinterpret_cast<short*>(&v);
}

// Input-dtype probe: flag=1 if bf16, 0 if fp32.
__global__ void dtype_probe(const unsigned* __restrict__ x, int* __restrict__ flag)
{
  int t = threadIdx.x;              // 64 threads
  int cnt = 0;
  #pragma unroll
  for (int k = 0; k < 4; k++) {
    unsigned w = x[t*4 + k];
    unsigned lo = w & 0xFFFFu;
    unsigned e  = (lo >> 7) & 0xFFu;
    if (lo == 0u || (e >= 90u && e <= 145u)) cnt++;
  }
  #pragma unroll
  for (int off = 32; off; off >>= 1) cnt += __shfl_down(cnt, off);
  if (t == 0) *flag = (cnt >= 160) ? 1 : 0;
}

// Fused 5-projection kernel (scalar FMA; fp32 path + small-ws fallback).
template<typename TI>
__global__ __launch_bounds__(256) void proj_kern(
    const int* __restrict__ gate, int want, const TI* __restrict__ x,
    const TI* __restrict__ W0, const TI* __restrict__ b0,
    const TI* __restrict__ W1, const TI* __restrict__ b1,
    const TI* __restrict__ W2, const TI* __restrict__ b2,
    const TI* __restrict__ W3, const TI* __restrict__ b3,
    const TI* __restrict__ W4, const TI* __restrict__ b4,
    bf16* __restrict__ tproj)
{
  if (*gate != want) return;
  const TI* Ws[5] = {W0, W1, W2, W3, W4};
  const TI* bs[5] = {b0, b1, b2, b3, b4};
  const int bz = blockIdx.z, j = bz >> 3, n = bz & 7;
  const TI* B    = Ws[j] + (size_t)n * 32768;
  const TI* bias = bs[j] + n * 64;
  bf16* out = tproj + (size_t)j * 131072;
  const int m0 = blockIdx.y * 64;
  __shared__ float As[16][68];
  __shared__ float Bs[16][68];
  const int t = threadIdx.x, tx = t & 15, ty = t >> 4;
  float acc[4][4] = {};
  for (int k0 = 0; k0 < 512; k0 += 16) {
    { int m = t >> 2, kk = (t & 3) * 4;
      const TI* ap = x + (size_t)(m0 + m) * 512 + (k0 + kk);
      float a0 = ldf(ap+0), a1 = ldf(ap+1), a2 = ldf(ap+2), a3 = ldf(ap+3);
      As[kk+0][m] = a0; As[kk+1][m] = a1; As[kk+2][m] = a2; As[kk+3][m] = a3; }
    { int kk = t >> 4, nn = (t & 15) * 4;
      const TI* bp = B + (size_t)(k0 + kk) * 64 + nn;
      Bs[kk][nn+0] = ldf(bp+0); Bs[kk][nn+1] = ldf(bp+1);
      Bs[kk][nn+2] = ldf(bp+2); Bs[kk][nn+3] = ldf(bp+3); }
    __syncthreads();
    #pragma unroll
    for (int kk = 0; kk < 16; kk++) {
      float4 a4 = *reinterpret_cast<const float4*>(&As[kk][ty*4]);
      float4 b4 = *reinterpret_cast<const float4*>(&Bs[kk][tx*4]);
      float av[4] = {a4.x,a4.y,a4.z,a4.w}, bv[4] = {b4.x,b4.y,b4.z,b4.w};
      #pragma unroll
      for (int im = 0; im < 4; im++)
        #pragma unroll
        for (int in = 0; in < 4; in++) acc[im][in] += av[im] * bv[in];
    }
    __syncthreads();
  }
  #pragma unroll
  for (int im = 0; im < 4; im++)
    #pragma unroll
    for (int in = 0; in < 4; in++) {
      float v = acc[im][in] + ldf(bias + tx*4 + in);
      int p = m0 + ty*4 + im, h = tx*4 + in;
      if (j < 3) out[(size_t)p * 512 + n*64 + h] = __float2bfloat16(v);
      else       out[(size_t)n * 16384 + (size_t)h * 256 + p] = __float2bfloat16(v);
    }
}

// wtrans5: WT[jn][h][512 d] = W_j[n][d][h]  (64x64 LDS tile transpose).
__global__ __launch_bounds__(256) void wtrans5(
    const int* __restrict__ gate,
    const bf16* __restrict__ W0, const bf16* __restrict__ W1,
    const bf16* __restrict__ W2, const bf16* __restrict__ W3,
    const bf16* __restrict__ W4, bf16* __restrict__ WT)
{
  if (*gate != 1) return;
  const bf16* Ws[5] = {W0, W1, W2, W3, W4};
  const int jn = blockIdx.y, j = jn >> 3, n = jn & 7, d0 = blockIdx.x * 64;
  const bf16* src = Ws[j] + (size_t)n * 32768;   // [512 d][64 h]
  __shared__ short tile[64][72];
  const int t = threadIdx.x;
  #pragma unroll
  for (int pp = 0; pp < 2; pp++) {
    int r = (t >> 3) + pp*32, h8 = (t & 7) * 8;
    *reinterpret_cast<short8*>(&tile[r][h8]) = ld_g8(src + (size_t)(d0 + r)*64 + h8);
  }
  __syncthreads();
  #pragma unroll
  for (int pp = 0; pp < 2; pp++) {
    int h = (t >> 3) + pp*32, d8 = (t & 7) * 8;
    short8 v;
    #pragma unroll
    for (int k = 0; k < 8; k++) v[k] = tile[d8 + k][h];
    *reinterpret_cast<short8*>(WT + ((size_t)jn*64 + h)*512 + d0 + d8) = v;
  }
}

// wotrans: WOT[d][k] = WO[k][d], 512x512 (k = n*64+h flattened).
__global__ __launch_bounds__(256) void wotrans(
    const int* __restrict__ gate, const bf16* __restrict__ WO,
    bf16* __restrict__ WOT)
{
  if (*gate != 1) return;
  const int k0 = blockIdx.y * 64, d0 = blockIdx.x * 64;
  __shared__ short tile[64][72];
  const int t = threadIdx.x;
  #pragma unroll
  for (int pp = 0; pp < 2; pp++) {
    int r = (t >> 3) + pp*32, c8 = (t & 7) * 8;
    *reinterpret_cast<short8*>(&tile[r][c8]) = ld_g8(WO + (size_t)(k0 + r)*512 + d0 + c8);
  }
  __syncthreads();
  #pragma unroll
  for (int pp = 0; pp < 2; pp++) {
    int d = (t >> 3) + pp*32, k8 = (t & 7) * 8;
    short8 v;
    #pragma unroll
    for (int k = 0; k < 8; k++) v[k] = tile[k8 + k][d];
    *reinterpret_cast<short8*>(WOT + (size_t)(d0 + d)*512 + k0 + k8) = v;
  }
}

// proj_mfma (bf16/bigws): t_j[p,n,h] via MFMA; B-frags from WT (k-contig).
__global__ __launch_bounds__(256) void proj_mfma(
    const int* __restrict__ gate, const bf16* __restrict__ x,
    const bf16* __restrict__ WT,
    const bf16* __restrict__ b0, const bf16* __restrict__ b1,
    const bf16* __restrict__ b2, const bf16* __restrict__ b3,
    const bf16* __restrict__ b4, bf16* __restrict__ tproj)
{
  if (*gate != 1) return;
  const bf16* bs[5] = {b0, b1, b2, b3, b4};
  const int jn = blockIdx.y, j = jn >> 3, n = jn & 7;
  const int t = threadIdx.x, wid = t >> 6, lane = t & 63, quad = lane >> 4, l16 = lane & 15;
  const int pb = blockIdx.x * 64 + wid * 16;
  const bf16* bias = bs[j] + n * 64;
  floatx4 acc[4];
  #pragma unroll
  for (int jt = 0; jt < 4; jt++) acc[jt] = (floatx4){0.f, 0.f, 0.f, 0.f};
  for (int kc = 0; kc < 16; kc++) {
    short8 af = ld_g8(x + (size_t)(pb + l16)*512 + kc*32 + quad*8);
    #pragma unroll
    for (int jt = 0; jt < 4; jt++) {
      short8 bf = ld_g8(WT + ((size_t)jn*64 + jt*16 + l16)*512 + kc*32 + quad*8);
      acc[jt] = mfma16(af, bf, acc[jt]);
    }
  }
  bf16* out = tproj + (size_t)j * 131072;
  #pragma unroll
  for (int jt = 0; jt < 4; jt++) {
    float bv = ldf(bias + jt*16 + l16);
    #pragma unroll
    for (int reg = 0; reg < 4; reg++) {
      int p = pb + quad*4 + reg, h = jt*16 + l16;
      float v = acc[jt][reg] + bv;
      if (j < 3) out[(size_t)p * 512 + n*64 + h] = __float2bfloat16(v);
      else       out[(size_t)n * 16384 + (size_t)h * 256 + p] = __float2bfloat16(v);
    }
  }
}

// out_mfma (bf16/bigws): out[q][d] = zbb[q,:]·WOT[d,:] + bO[d].
__global__ __launch_bounds__(256) void out_mfma(
    const int* __restrict__ gate, const bf16* __restrict__ zbb,
    const bf16* __restrict__ WOT, const bf16* __restrict__ bO,
    bf16* __restrict__ out)
{
  if (*gate != 1) return;
  const int d0 = blockIdx.x * 64;
  const int t = threadIdx.x, wid = t >> 6, lane = t & 63, quad = lane >> 4, l16 = lane & 15;
  const int qb = blockIdx.y * 64 + wid * 16;
  floatx4 acc[4];
  #pragma unroll
  for (int jt = 0; jt < 4; jt++) acc[jt] = (floatx4){0.f, 0.f, 0.f, 0.f};
  for (int kc = 0; kc < 16; kc++) {
    short8 af = ld_g8(zbb + (size_t)(qb + l16)*512 + kc*32 + quad*8);
    #pragma unroll
    for (int jt = 0; jt < 4; jt++) {
      short8 bf = ld_g8(WOT + (size_t)(d0 + jt*16 + l16)*512 + kc*32 + quad*8);
      acc[jt] = mfma16(af, bf, acc[jt]);
    }
  }
  #pragma unroll
  for (int jt = 0; jt < 4; jt++) {
    float bv = ldf(bO + d0 + jt*16 + l16);
    #pragma unroll
    for (int reg = 0; reg < 4; reg++)
      out[(size_t)(qb + quad*4 + reg)*512 + d0 + jt*16 + l16] =
          __float2bfloat16(acc[jt][reg] + bv);
  }
}

// MFMA s1t: s1t[r][(i,j)] = sum_{n,k} tc[r][(n,k)] * W_K[n][i][j][k].
template<typename TW>
__global__ __launch_bounds__(256) void s1t_mfma(
    const int* __restrict__ gate, int want,
    const bf16* __restrict__ tc, const TW* __restrict__ WK, bf16* __restrict__ s1t)
{
  if (*gate != want) return;
  const int i = blockIdx.x;
  const int t = threadIdx.x, wid = t >> 6, lane = t & 63, quad = lane >> 4, l16 = lane & 15;
  const int rw = blockIdx.y * 64 + wid * 16;
  floatx4 acc[4];
  #pragma unroll
  for (int jt = 0; jt < 4; jt++) acc[jt] = (floatx4){0.f, 0.f, 0.f, 0.f};
  for (int kc = 0; kc < 16; kc++) {
    short8 af = ld_g8(tc + (size_t)(rw + l16) * 512 + kc*32 + quad*8);
    const int n = kc >> 1, kk = (kc & 1) * 32 + quad * 8;
    #pragma unroll
    for (int jt = 0; jt < 4; jt++) {
      const TW* bp = WK + ((size_t)(n*64 + i) * 64 + jt*16 + l16) * 64 + kk;
      short8 bf;
      if constexpr (sizeof(TW) == 2) {
        bf = ld_g8((const bf16*)bp);
      } else {
        float4 x0 = *reinterpret_cast<const float4*>(bp);
        float4 x1 = *reinterpret_cast<const float4*>(bp + 4);
        bf[0]=bfs(x0.x); bf[1]=bfs(x0.y); bf[2]=bfs(x0.z); bf[3]=bfs(x0.w);
        bf[4]=bfs(x1.x); bf[5]=bfs(x1.y); bf[6]=bfs(x1.z); bf[7]=bfs(x1.w);
      }
      acc[jt] = mfma16(af, bf, acc[jt]);
    }
  }
  #pragma unroll
  for (int jt = 0; jt < 4; jt++)
    #pragma unroll
    for (int reg = 0; reg < 4; reg++)
      s1t[(size_t)(rw + quad*4 + reg) * 4096 + i*64 + jt*16 + l16] =
          __float2bfloat16(acc[jt][reg]);
}

// Generic 64x64-tile GEMM (scalar; fp32 path + small-ws fallback).
template<typename TA, typename TB, typename TC, bool BIAS>
__global__ __launch_bounds__(256) void gemm_tile(
    const int* __restrict__ gate, int want,
    const TA* __restrict__ A, const TB* __restrict__ B, TC* __restrict__ C,
    const TB* __restrict__ bias,
    int Ncols, int K, int lda, int ldc)
{
  if (*gate != want) return;
  const int m0 = blockIdx.y * 64, n0 = blockIdx.x * 64;
  __shared__ float As[16][68];
  __shared__ float Bs[16][68];
  const int t = threadIdx.x, tx = t & 15, ty = t >> 4;
  float acc[4][4] = {};
  for (int k0 = 0; k0 < K; k0 += 16) {
    { int m = t >> 2, kk = (t & 3) * 4;
      const TA* ap = A + (size_t)(m0 + m) * lda + (k0 + kk);
      float a0 = ldf(ap+0), a1 = ldf(ap+1), a2 = ldf(ap+2), a3 = ldf(ap+3);
      As[kk+0][m] = a0; As[kk+1][m] = a1; As[kk+2][m] = a2; As[kk+3][m] = a3; }
    { int kk = t >> 4, nn = (t & 15) * 4;
      const TB* bp = B + (size_t)(k0 + kk) * Ncols + (n0 + nn);
      Bs[kk][nn+0] = ldf(bp+0); Bs[kk][nn+1] = ldf(bp+1);
      Bs[kk][nn+2] = ldf(bp+2); Bs[kk][nn+3] = ldf(bp+3); }
    __syncthreads();
    #pragma unroll
    for (int kk = 0; kk < 16; kk++) {
      float4 a4 = *reinterpret_cast<const float4*>(&As[kk][ty*4]);
      float4 b4 = *reinterpret_cast<const float4*>(&Bs[kk][tx*4]);
      float av[4] = {a4.x,a4.y,a4.z,a4.w}, bv[4] = {b4.x,b4.y,b4.z,b4.w};
      #pragma unroll
      for (int im = 0; im < 4; im++)
        #pragma unroll
        for (int in = 0; in < 4; in++) acc[im][in] += av[im] * bv[in];
    }
    __syncthreads();
  }
  #pragma unroll
  for (int im = 0; im < 4; im++) {
    TC* cp = C + (size_t)(m0 + ty*4 + im) * ldc + n0 + tx*4;
    #pragma unroll
    for (int in = 0; in < 4; in++) {
      float v = acc[im][in];
      if constexpr (BIAS) v += ldf(bias + n0 + tx*4 + in);
      stf(cp + in, v);
    }
  }
}

// tbs[q][j] = (1/64) * sum_n tb[q][n][j]  -> bf16 [q][64]
__global__ __launch_bounds__(256) void tbs_kern(const bf16* __restrict__ tb,
                                                bf16* __restrict__ tbsbf)
{
  int t = blockIdx.x * 256 + threadIdx.x;
  int q = t >> 6, j = t & 63;
  float s = 0.f;
  #pragma unroll
  for (int n = 0; n < 8; n++) s += ldf(tb + q*512 + n*64 + j);
  tbsbf[t] = __float2bfloat16(s * 0.015625f);
}

// c_kern: cpack[off(r)+q][i] = tbs[q,:]·s1t[r][i,:]  (raw, no masking).
__global__ __launch_bounds__(256) void c_kern(
    const bf16* __restrict__ tbsbf, const bf16* __restrict__ s1t,
    bf16* __restrict__ cpack)
{
  const int r = blockIdx.y;
  const int a = r >> 5;
  const int rows = 32 * (a + 1);
  const int q0 = blockIdx.x * 64;
  if (q0 >= rows) return;
  const int t = threadIdx.x, wid = t >> 6, lane = t & 63, quad = lane >> 4, l16 = lane & 15;
  const int qw = wid * 16;
  if (q0 + qw >= rows) return;        // wave writes [q0+qw, q0+qw+16) -- clamp
  const bf16* s1r = s1t + (size_t)r * 4096;
  bf16* cp = cpack + ((size_t)rows * (16*a + (r & 31)) + q0) * 64;
  short8 af0 = ld_g8(tbsbf + (size_t)(q0 + qw + l16) * 64 + quad*8);
  short8 af1 = ld_g8(tbsbf + (size_t)(q0 + qw + l16) * 64 + 32 + quad*8);
  #pragma unroll
  for (int it = 0; it < 4; it++) {
    floatx4 acc = {0.f, 0.f, 0.f, 0.f};
    acc = mfma16(af0, ld_g8(s1r + (it*16 + l16)*64 + quad*8), acc);
    acc = mfma16(af1, ld_g8(s1r + (it*16 + l16)*64 + 32 + quad*8), acc);
    #pragma unroll
    for (int reg = 0; reg < 4; reg++)
      cp[(size_t)(qw + quad*4 + reg) * 64 + it*16 + l16] = __float2bfloat16(acc[reg]);
  }
}

// ---------------- tri_attn v1 (small-ws fallback; round-12 verbatim) --------
__global__ __launch_bounds__(256) void tri_attn(
    const bf16* __restrict__ ta, const bf16* __restrict__ tbsbf,
    const bf16* __restrict__ s1t, const bf16* __restrict__ tdT,
    const bf16* __restrict__ teT, bf16* __restrict__ Sbuf)
{
  __shared__ __align__(16) char smb[39936];
  const int bx = blockIdx.x;
  const int n = bx & 7;
  const int r = 255 - (bx >> 3);
  const int t = threadIdx.x;
  const int wid = t >> 6, lane = t & 63, quad = lane >> 4, l16 = lane & 15;
  bf16* srow = Sbuf + (size_t)n * 1048576 + (size_t)r * 4096;
  if (r < 2) {
    short8 zz = (short8){0,0,0,0,0,0,0,0};
    reinterpret_cast<short8*>(srow)[t]       = zz;
    reinterpret_cast<short8*>(srow)[t + 256] = zz;
    return;
  }
  const int nch  = ((r - 1) >> 5) + 1;
  const int rcap = nch * 32;
  {
    const bf16* s1r = s1t + (size_t)r * 4096;
    short8 bfr[4][2];
    #pragma unroll
    for (int it = 0; it < 4; it++)
      #pragma unroll
      for (int kc = 0; kc < 2; kc++)
        bfr[it][kc] = ld_g8(s1r + (it*16 + l16)*64 + kc*32 + quad*8);
    #pragma unroll
    for (int qt = 0; qt < 4; qt++) {
      const int q0 = wid * 64 + qt * 16;
      if (q0 >= rcap) continue;
      if (q0 >= r) {
        #pragma unroll
        for (int it = 0; it < 4; it++)
          #pragma unroll
          for (int reg = 0; reg < 4; reg++) {
            int q = q0 + quad*4 + reg;
            *reinterpret_cast<bf16*>(smb + q*136 + (it*16 + l16)*2) =
                __float2bfloat16(0.f);
          }
        continue;
      }
      short8 af0 = ld_g8(tbsbf + (q0 + l16)*64 + quad*8);
      short8 af1 = ld_g8(tbsbf + (q0 + l16)*64 + 32 + quad*8);
      #pragma unroll
      for (int it = 0; it < 4; it++) {
        floatx4 acc = {0.f, 0.f, 0.f, 0.f};
        acc = mfma16(af0, bfr[it][0], acc);
        acc = mfma16(af1, bfr[it][1], acc);
        #pragma unroll
        for (int reg = 0; reg < 4; reg++) {
          int q = q0 + quad*4 + reg;
          float v = (q >= 1 && q < r) ? acc[reg] : 0.f;
          *reinterpret_cast<bf16*>(smb + q*136 + (it*16 + l16)*2) = __float2bfloat16(v);
        }
      }
    }
  }
  short8 taf[4][2];
  #pragma unroll
  for (int pt = 0; pt < 4; pt++)
    #pragma unroll
    for (int kc = 0; kc < 2; kc++)
      taf[pt][kc] = ld_g8(ta + (size_t)((pt*4 + wid)*16 + l16)*512 + n*64
                             + kc*32 + quad*8);
  __syncthreads();

  floatx4 Tacc[4][4];
  #pragma unroll
  for (int pt = 0; pt < 4; pt++)
    #pragma unroll
    for (int gt = 0; gt < 4; gt++) Tacc[pt][gt] = (floatx4){0.f, 0.f, 0.f, 0.f};
  float Zp = 0.f;
  char* EwB = smb + 34816 + wid * 1152;
  for (int ch = 0; ch < nch; ch++) {
    const int qc = ch * 32;
    if (qc + 31 <= wid * 16) continue;
    short8 cfr[2][2];
    #pragma unroll
    for (int qt2 = 0; qt2 < 2; qt2++)
      #pragma unroll
      for (int kc = 0; kc < 2; kc++)
        cfr[qt2][kc] = *reinterpret_cast<const short8*>(
            smb + (qc + qt2*16 + l16)*136 + (kc*32 + quad*8)*2);
    short8 tef[4];
    #pragma unroll
    for (int gt = 0; gt < 4; gt++)
      tef[gt] = ld_g8(teT + (size_t)n*16384 + (gt*16 + l16)*256 + qc + quad*8);
    #pragma unroll
    for (int pt = 0; pt < 4; pt++) {
      const int ptb = (pt*4 + wid) * 16;
      if (ptb >= qc + 31) continue;
      #pragma unroll
      for (int qt2 = 0; qt2 < 2; qt2++) {
        const int qh = qc + qt2*16;
        char* erow0 = EwB + (quad*4)*72 + (qt2*16 + l16)*2;
        if (qh + 15 <= ptb) {
          #pragma unroll
          for (int reg = 0; reg < 4; reg++)
            *reinterpret_cast<bf16*>(erow0 + reg*72) = __float2bfloat16(0.f);
        } else {
          floatx4 acc = {0.f, 0.f, 0.f, 0.f};
          acc = mfma16(taf[pt][0], cfr[qt2][0], acc);
          acc = mfma16(taf[pt][1], cfr[qt2][1], acc);
          if (qh >= ptb + 16 && qh + 15 < r) {
            #pragma unroll
            for (int reg = 0; reg < 4; reg++) {
              float e = __expf(acc[reg]);
              Zp += e;
              *reinterpret_cast<bf16*>(erow0 + reg*72) = __float2bfloat16(e);
            }
          } else {
            #pragma unroll
            for (int reg = 0; reg < 4; reg++) {
              int p = ptb + quad*4 + reg;
              int q = qh + l16;
              float e = (p < q && q < r) ? __expf(acc[reg]) : 0.f;
              Zp += e;
              *reinterpret_cast<bf16*>(erow0 + reg*72) = __float2bfloat16(e);
            }
          }
        }
      }
      short8 ef = *reinterpret_cast<const short8*>(EwB + l16*72 + quad*16);
      __builtin_amdgcn_s_setprio(1);
      #pragma unroll
      for (int gt = 0; gt < 4; gt++)
        Tacc[pt][gt] = mfma16(ef, tef[gt], Tacc[pt][gt]);
      __builtin_amdgcn_s_setprio(0);
    }
  }
  #pragma unroll
  for (int off = 32; off; off >>= 1) Zp += __shfl_down(Zp, off);
  float* scr = reinterpret_cast<float*>(smb + 39424);
  if (lane == 0) scr[wid] = Zp;
  __syncthreads();
  const float rinv = 1.f / (scr[0] + scr[1] + scr[2] + scr[3]);

  #pragma unroll
  for (int pt = 0; pt < 4; pt++) {
    if ((pt*4 + wid)*16 >= rcap) continue;
    #pragma unroll
    for (int gt = 0; gt < 4; gt++)
      #pragma unroll
      for (int reg = 0; reg < 4; reg++) {
        int g = gt*16 + l16;
        int p = (pt*4 + wid)*16 + quad*4 + reg;
        *reinterpret_cast<bf16*>(smb + g*528 + p*2) = __float2bfloat16(Tacc[pt][gt][reg]);
      }
  }
  __syncthreads();

  {
    short8 Taf[8];
    #pragma unroll
    for (int kc = 0; kc < 8; kc++)
      if (kc < nch)
        Taf[kc] = *reinterpret_cast<const short8*>(
            smb + (wid*16 + l16)*528 + (kc*32 + quad*8)*2);
    #pragma unroll
    for (int ht = 0; ht < 4; ht++) {
      floatx4 acc = {0.f, 0.f, 0.f, 0.f};
      __builtin_amdgcn_s_setprio(1);
      #pragma unroll
      for (int kc = 0; kc < 8; kc++) {
        if (kc < nch) {
          short8 bfragd = ld_g8(tdT + (size_t)n*16384 + (ht*16 + l16)*256 + kc*32 + quad*8);
          acc = mfma16(Taf[kc], bfragd, acc);
        }
      }
      __builtin_amdgcn_s_setprio(0);
      #pragma unroll
      for (int reg = 0; reg < 4; reg++) {
        int g = wid*16 + quad*4 + reg, h = ht*16 + l16;
        srow[h*64 + g] = __float2bfloat16(acc[reg] * rinv);
      }
    }
  }
}

// ---------------- tri_attn2 (bigws path; round-14 verbatim) -----------------
__global__ __launch_bounds__(256) void tri_attn2(
    const bf16* __restrict__ ta, const bf16* __restrict__ cpack,
    const bf16* __restrict__ tdT, const bf16* __restrict__ teT,
    bf16* __restrict__ Sbuf)
{
  __shared__ __align__(16) char smb[22528];
  const int bx = blockIdx.x;
  const int n = bx & 7;
  const int r = 255 - (bx >> 3);
  const int t = threadIdx.x;
  const int wid = t >> 6, lane = t & 63, quad = lane >> 4, l16 = lane & 15;
  bf16* srow = Sbuf + (size_t)n * 1048576 + (size_t)r * 4096;
  if (r < 2) {
    short8 zz = (short8){0,0,0,0,0,0,0,0};
    reinterpret_cast<short8*>(srow)[t]       = zz;
    reinterpret_cast<short8*>(srow)[t + 256] = zz;
    return;
  }
  const int nch  = ((r - 1) >> 5) + 1;
  const int rcap = nch * 32;
  const int ra = r >> 5;
  const bf16* cp = cpack + (size_t)(32 * (ra + 1)) * (16*ra + (r & 31)) * 64;

  short8 taf[4][2];
  #pragma unroll
  for (int pt = 0; pt < 4; pt++)
    #pragma unroll
    for (int kc = 0; kc < 2; kc++)
      taf[pt][kc] = ld_g8(ta + (size_t)((pt*4 + wid)*16 + l16)*512 + n*64
                             + kc*32 + quad*8);

  floatx4 Tacc[4][4];
  #pragma unroll
  for (int pt = 0; pt < 4; pt++)
    #pragma unroll
    for (int gt = 0; gt < 4; gt++) Tacc[pt][gt] = (floatx4){0.f, 0.f, 0.f, 0.f};
  float Zp = 0.f;
  char* EwB = smb + 17408 + wid * 1152;
  for (int ch = 0; ch < nch; ch++) {
    const int qc = ch * 32;
    if (qc + 31 <= wid * 16) continue;
    short8 cfr[2][2];
    #pragma unroll
    for (int qt2 = 0; qt2 < 2; qt2++)
      #pragma unroll
      for (int kc = 0; kc < 2; kc++)
        cfr[qt2][kc] = ld_g8(cp + (size_t)(qc + qt2*16 + l16)*64 + kc*32 + quad*8);
    short8 tef[4];
    #pragma unroll
    for (int gt = 0; gt < 4; gt++)
      tef[gt] = ld_g8(teT + (size_t)n*16384 + (gt*16 + l16)*256 + qc + quad*8);
    #pragma unroll
    for (int pt = 0; pt < 4; pt++) {
      const int ptb = (pt*4 + wid) * 16;
      if (ptb >= qc + 31) continue;
      #pragma unroll
      for (int qt2 = 0; qt2 < 2; qt2++) {
        const int qh = qc + qt2*16;
        char* erow0 = EwB + (quad*4)*72 + (qt2*16 + l16)*2;
        if (qh + 15 <= ptb) {
          #pragma unroll
          for (int reg = 0; reg < 4; reg++)
            *reinterpret_cast<bf16*>(erow0 + reg*72) = __float2bfloat16(0.f);
        } else {
          floatx4 acc = {0.f, 0.f, 0.f, 0.f};
          acc = mfma16(taf[pt][0], cfr[qt2][0], acc);
          acc = mfma16(taf[pt][1], cfr[qt2][1], acc);
          if (qh >= ptb + 16 && qh + 15 < r) {
            #pragma unroll
            for (int reg = 0; reg < 4; reg++) {
              float e = __expf(acc[reg]);
              Zp += e;
              *reinterpret_cast<bf16*>(erow0 + reg*72) = __float2bfloat16(e);
            }
          } else {
            #pragma unroll
            for (int reg = 0; reg < 4; reg++) {
              int p = ptb + quad*4 + reg;
              int q = qh + l16;
              float e = (p < q && q < r) ? __expf(acc[reg]) : 0.f;
              Zp += e;
              *reinterpret_cast<bf16*>(erow0 + reg*72) = __float2bfloat16(e);
            }
          }
        }
      }
      short8 ef = *reinterpret_cast<const short8*>(EwB + l16*72 + quad*16);
      __builtin_amdgcn_s_setprio(1);
      #pragma unroll
      for (int gt = 0; gt < 4; gt++)
        Tacc[pt][gt] = mfma16(ef, tef[gt], Tacc[pt][gt]);
      __builtin_amdgcn_s_setprio(0);
    }
  }
  #pragma unroll
  for (int off = 32; off; off >>= 1) Zp += __shfl_down(Zp, off);
  float* scr = reinterpret_cast<float*>(smb + 22016);
  if (lane == 0) scr[wid] = Zp;
  __syncthreads();
  const float rinv = 1.f / (scr[0] + scr[1] + scr[2] + scr[3]);

  floatx4 Sacc[4];
  #pragma unroll
  for (int ht = 0; ht < 4; ht++) Sacc[ht] = (floatx4){0.f, 0.f, 0.f, 0.f};
  #pragma unroll
  for (int h2 = 0; h2 < 2; h2++) {
    if (h2 * 128 < rcap) {
      __syncthreads();
      #pragma unroll
      for (int pt2 = 0; pt2 < 2; pt2++) {
        const int pt = h2*2 + pt2;
        const int pbase = (pt*4 + wid) * 16;
        if (pbase >= rcap) continue;
        const int pl = pbase - h2*128;
        #pragma unroll
        for (int gt = 0; gt < 4; gt++)
          #pragma unroll
          for (int reg = 0; reg < 4; reg++) {
            int g = gt*16 + l16;
            *reinterpret_cast<bf16*>(smb + g*272 + (pl + quad*4 + reg)*2) =
                __float2bfloat16(Tacc[pt][gt][reg]);
          }
      }
      __syncthreads();
      short8 Taf[4];
      #pragma unroll
      for (int kcl = 0; kcl < 4; kcl++)
        if (h2*4 + kcl < nch)
          Taf[kcl] = *reinterpret_cast<const short8*>(
              smb + (wid*16 + l16)*272 + (kcl*32 + quad*8)*2);
      __builtin_amdgcn_s_setprio(1);
      #pragma unroll
      for (int ht = 0; ht < 4; ht++) {
        #pragma unroll
        for (int kcl = 0; kcl < 4; kcl++) {
          const int kc = h2*4 + kcl;
          if (kc < nch) {
            short8 bfragd = ld_g8(tdT + (size_t)n*16384 + (ht*16 + l16)*256
                                      + kc*32 + quad*8);
            Sacc[ht] = mfma16(Taf[kcl], bfragd, Sacc[ht]);
          }
        }
      }
      __builtin_amdgcn_s_setprio(0);
    }
  }
  #pragma unroll
  for (int ht = 0; ht < 4; ht++)
    #pragma unroll
    for (int reg = 0; reg < 4; reg++) {
      int g = wid*16 + quad*4 + reg, h = ht*16 + l16;
      srow[h*64 + g] = __float2bfloat16(Sacc[ht][reg] * rinv);
    }
}

// z_kern split-K: zpart[ks][r][n*64+f] = sum_{k in slice} S'[n][r][k]*WV[n][k][f].
template<typename TW>
__global__ __launch_bounds__(256) void z_kern(
    const int* __restrict__ gate, int want,
    const bf16* __restrict__ Sbuf, const TW* __restrict__ WV,
    float* __restrict__ zpart, int kslice)
{
  if (*gate != want) return;
  __shared__ __align__(16) char lds[32 * 136];
  const int rt = blockIdx.x, n = blockIdx.y, ks = blockIdx.z;
  const int t = threadIdx.x, wid = t >> 6, lane = t & 63, quad = lane >> 4, l16 = lane & 15;
  const int rw = rt * 64 + wid * 16;
  const int k0 = ks * kslice;
  const TW*  wvn = WV   + (size_t)n * 262144;
  const bf16* sn = Sbuf + (size_t)n * 1048576;
  floatx4 acc[4];
  #pragma unroll
  for (int ft = 0; ft < 4; ft++) acc[ft] = (floatx4){0.f, 0.f, 0.f, 0.f};
  const int row = t >> 3, f8 = (t & 7) * 8;
  for (int kb = k0; kb < k0 + kslice; kb += 32) {
    { const TW* src = wvn + (size_t)(kb + row) * 64 + f8;
      short sv[8];
      if constexpr (sizeof(TW) == 2) {
        short8 v = ld_g8((const bf16*)src);
        #pragma unroll
        for (int j = 0; j < 8; j++) sv[j] = v[j];
      } else {
        float4 a = *reinterpret_cast<const float4*>(src);
        float4 b = *reinterpret_cast<const float4*>(src + 4);
        sv[0]=bfs(a.x); sv[1]=bfs(a.y); sv[2]=bfs(a.z); sv[3]=bfs(a.w);
        sv[4]=bfs(b.x); sv[5]=bfs(b.y); sv[6]=bfs(b.z); sv[7]=bfs(b.w);
      }
      short* dst = reinterpret_cast<short*>(lds + row*136 + f8*2);
      s16x4 lo = {sv[0],sv[1],sv[2],sv[3]}, hi = {sv[4],sv[5],sv[6],sv[7]};
      *reinterpret_cast<s16x4*>(dst)     = lo;
      *reinterpret_cast<s16x4*>(dst + 4) = hi;
    }
    __syncthreads();
    short8 af = ld_g8(sn + (size_t)(rw + l16) * 4096 + kb + quad*8);
    #pragma unroll
    for (int ft = 0; ft < 4; ft++) {
      short8 bfv;
      #pragma unroll
      for (int j = 0; j < 8; j++)
        bfv[j] = *reinterpret_cast<const short*>(
            lds + (quad*8 + j)*136 + (ft*16 + l16)*2);
      acc[ft] = mfma16(af, bfv, acc[ft]);
    }
    __syncthreads();
  }
  float* zp = zpart + (size_t)ks * 131072;
  #pragma unroll
  for (int ft = 0; ft < 4; ft++)
    #pragma unroll
    for (int reg = 0; reg < 4; reg++)
      zp[(size_t)(rw + quad*4 + reg) * 512 + n*64 + ft*16 + l16] = acc[ft][reg];
}

// zred: zbb[idx] = bf16( sum_ks zpart[ks][idx] ), idx over 256*512.
__global__ __launch_bounds__(256) void zred_kern(
    const float* __restrict__ zpart, bf16* __restrict__ zbb, int ks)
{
  int idx = blockIdx.x * 256 + threadIdx.x;   // 512 blocks
  float s = 0.f;
  for (int k = 0; k < ks; k++) s += zpart[(size_t)k * 131072 + idx];
  zbb[idx] = __float2bfloat16(s);
}

extern "C" void kernel_launch(void* const* d_in, const int* in_sizes, int n_in,
                              void* d_out, int out_size, void* d_ws, size_t ws_size,
                              hipStream_t stream)
{
  (void)in_sizes; (void)n_in; (void)out_size;
  char* wsb = (char*)d_ws;
  const long TE = 131072;
  const bool bigws = (ws_size == 0) || (ws_size >= 25165824);  // ws_size const per session

  int* flag; bf16 *tproj, *tbsbf, *s1t, *zbb, *Sbuf, *cpack; float* zpart; int ks;
  bf16 *WT = nullptr, *WOT = nullptr;
  if (bigws) {
    // bigws layout (peak = 25165824):
    //  flag [0,4); tproj [4096,1314816); tbsbf [1314816,1347584)
    //  s1t [1347584,3444736); cpack [3444736,8163328)
    //  WT bf16 [3444736,6066176) (dead after proj_mfma; cpack overwrites)
    //  zpart fp32 [3444736,7639040) / zbb [7639040,7901184) overlap cpack
    //  Sbuf [8388608,25165824); WOT [8388608,8912896) (written AFTER z_kern)
    flag  = (int*)wsb;
    tproj = (bf16*)(wsb + 4096);
    tbsbf = (bf16*)(wsb + 1314816);
    s1t   = (bf16*)(wsb + 1347584);
    cpack = (bf16*)(wsb + 3444736);
    WT    = (bf16*)(wsb + 3444736);
    zpart = (float*)(wsb + 3444736);
    zbb   = (bf16*)(wsb + 7639040);
    Sbuf  = (bf16*)(wsb + 8388608);
    WOT   = (bf16*)(wsb + 8388608);
    ks    = 8;
  } else {
    flag  = (int*)wsb;
    tproj = (bf16*)(wsb + 256);
    tbsbf = (bf16*)(wsb + 1310976);
    s1t   = (bf16*)(wsb + 1343744);
    zbb   = (bf16*)(wsb + 3440896);
    Sbuf  = (bf16*)(wsb + 4194304);
    cpack = nullptr;
    zpart = (float*)(wsb + 1343744);
    ks    = 2;
  }
  const int kslice = 4096 / ks;

  dtype_probe<<<1, 64, 0, stream>>>((const unsigned*)d_in[0], flag);

  if (bigws) {
    wtrans5<<<dim3(8,40), 256, 0, stream>>>(
        flag, (const bf16*)d_in[1], (const bf16*)d_in[3], (const bf16*)d_in[5],
        (const bf16*)d_in[7], (const bf16*)d_in[9], WT);
    proj_mfma<<<dim3(4,40), 256, 0, stream>>>(
        flag, (const bf16*)d_in[0], WT,
        (const bf16*)d_in[2], (const bf16*)d_in[4], (const bf16*)d_in[6],
        (const bf16*)d_in[8], (const bf16*)d_in[10], tproj);
  } else {
    proj_kern<bf16><<<dim3(1,4,40), 256, 0, stream>>>(
        flag, 1, (const bf16*)d_in[0],
        (const bf16*)d_in[1], (const bf16*)d_in[2], (const bf16*)d_in[3], (const bf16*)d_in[4],
        (const bf16*)d_in[5], (const bf16*)d_in[6], (const bf16*)d_in[7], (const bf16*)d_in[8],
        (const bf16*)d_in[9], (const bf16*)d_in[10], tproj);
  }
  proj_kern<float><<<dim3(1,4,40), 256, 0, stream>>>(
      flag, 0, (const float*)d_in[0],
      (const float*)d_in[1], (const float*)d_in[2], (const float*)d_in[3], (const float*)d_in[4],
      (const float*)d_in[5], (const float*)d_in[6], (const float*)d_in[7], (const float*)d_in[8],
      (const float*)d_in[9], (const float*)d_in[10], tproj);
  tbs_kern<<<64, 256, 0, stream>>>(tproj + 1*TE, tbsbf);
  s1t_mfma<bf16><<<dim3(64,4), 256, 0, stream>>>(
      flag, 1, tproj + 2*TE, (const bf16*)d_in[12], s1t);
  s1t_mfma<float><<<dim3(64,4), 256, 0, stream>>>(
      flag, 0, tproj + 2*TE, (const float*)d_in[12], s1t);
  if (bigws) {
    c_kern<<<dim3(4,256), 256, 0, stream>>>(tbsbf, s1t, cpack);
    tri_attn2<<<2048, 256, 0, stream>>>(
        tproj, cpack, tproj + 3*TE, tproj + 4*TE, Sbuf);
  } else {
    tri_attn<<<2048, 256, 0, stream>>>(
        tproj, tbsbf, s1t, tproj + 3*TE, tproj + 4*TE, Sbuf);
  }
  z_kern<bf16><<<dim3(4,8,ks), 256, 0, stream>>>(
      flag, 1, Sbuf, (const bf16*)d_in[11], zpart, kslice);
  z_kern<float><<<dim3(4,8,ks), 256, 0, stream>>>(
      flag, 0, Sbuf, (const float*)d_in[11], zpart, kslice);
  zred_kern<<<512, 256, 0, stream>>>(zpart, zbb, ks);
  if (bigws) {
    wotrans<<<dim3(8,8), 256, 0, stream>>>(flag, (const bf16*)d_in[13], WOT);
    out_mfma<<<dim3(8,4), 256, 0, stream>>>(
        flag, zbb, WOT, (const bf16*)d_in[14], (bf16*)d_out);
  } else {
    gemm_tile<bf16, bf16, bf16, true><<<dim3(8,4), 256, 0, stream>>>(
        flag, 1, zbb, (const bf16*)d_in[13], (bf16*)d_out, (const bf16*)d_in[14],
        512, 512, 512, 512);
  }
  gemm_tile<bf16, float, float, true><<<dim3(8,4), 256, 0, stream>>>(
      flag, 0, zbb, (const float*)d_in[13], (float*)d_out, (const float*)d_in[14],
      512, 512, 512, 512);
}

// Round 6
// 255.816 us; speedup vs baseline: 1.0874x; 1.0874x over previous
//
#include <hip/hip_runtime.h>
#include <hip/hip_bf16.h>

// TrittentionCube on MI355X. B=1, P=256, D=512, N=8, H=64. Round 16:
//  - REVERT to round-12 structure (best measured 267.5 us): tri_attn v1
//    (in-block phase 1), scalar proj/gemm, no cpack. Rounds 13-15 additions
//    (c_kern, MFMA proj/out, transposes) were net-negative: each extra
//    dispatch cost ~2.5-5 us and the replaced kernels were never hot.
//  - DISPATCH MERGE 12 -> 6: dtype_probe+gates replaced by per-wave in-kernel
//    dtype detection (ballot on first 64 words of x, threshold 40/64 -- >7
//    sigma from both dtype distributions); each dtype-dependent kernel
//    branches internally (wave-uniform). tbs folded into s1t_all as grid
//    row y==4. Sequence: proj_all, s1t_all(+tbs), tri_attn, z_all, zred,
//    gemm_all.
//  - All kernel bodies are round-12 verbatim; only dispatch topology changed
//    (isolates the launch-overhead variable).

typedef __hip_bfloat16 bf16;
typedef __attribute__((ext_vector_type(8))) short short8;
typedef __attribute__((ext_vector_type(4))) short s16x4;
typedef __attribute__((ext_vector_type(4))) float floatx4;

__device__ __forceinline__ float ldf(const float* p){ return *p; }
__device__ __forceinline__ float ldf(const bf16* p){ return __bfloat162float(*p); }
__device__ __forceinline__ void  stf(float* p, float v){ *p = v; }
__device__ __forceinline__ void  stf(bf16*  p, float v){ *p = __float2bfloat16(v); }

__device__ __forceinline__ floatx4 mfma16(short8 a, short8 b, floatx4 c){
  return __builtin_amdgcn_mfma_f32_16x16x32_bf16(a, b, c, 0, 0, 0);
}
__device__ __forceinline__ short8 ld_g8(const bf16* p){
  return *reinterpret_cast<const short8*>(p);
}
__device__ __forceinline__ short bfs(float x){
  bf16 v = __float2bfloat16(x);
  return *reinterpret_cast<short*>(&v);
}

// Wave-uniform dtype detect: true if x looks bf16. Reads words 0..63 (256 B).
// bf16 data: every lo-half is 0 or has exp in [90,145] -> cnt ~ 64/64.
// fp32 data: lo-half is mantissa bits -> cnt ~ 14 +/- 3.3. Threshold 40.
// All waves read the SAME words -> identical verdict everywhere.
__device__ __forceinline__ bool is_bf16_x(const void* xv)
{
  const unsigned* x32 = (const unsigned*)xv;
  unsigned w = x32[threadIdx.x & 63];
  unsigned lo = w & 0xFFFFu;
  unsigned e  = (lo >> 7) & 0xFFu;
  bool v = (lo == 0u) || (e >= 90u && e <= 145u);
  unsigned long long m = __ballot(v);
  return __popcll(m) >= 40;
}

// ---------------- proj_all: t_j[p,n,h] = x @ W_j[n] + b_j[n] ----------------
// j<3: [p][n*64+h]; j>=3: transposed [n][h][p]. Scalar-FMA body (round-12).
template<typename TI>
__device__ __forceinline__ void proj_body(
    const TI* __restrict__ x, const TI* const* Ws, const TI* const* bs,
    bf16* __restrict__ tproj, float* As, float* Bs)
{
  const int bz = blockIdx.z, j = bz >> 3, n = bz & 7;
  const TI* B    = Ws[j] + (size_t)n * 32768;
  const TI* bias = bs[j] + n * 64;
  bf16* out = tproj + (size_t)j * 131072;
  const int m0 = blockIdx.y * 64;
  const int t = threadIdx.x, tx = t & 15, ty = t >> 4;
  float acc[4][4] = {};
  for (int k0 = 0; k0 < 512; k0 += 16) {
    { int m = t >> 2, kk = (t & 3) * 4;
      const TI* ap = x + (size_t)(m0 + m) * 512 + (k0 + kk);
      float a0 = ldf(ap+0), a1 = ldf(ap+1), a2 = ldf(ap+2), a3 = ldf(ap+3);
      As[(kk+0)*68+m] = a0; As[(kk+1)*68+m] = a1;
      As[(kk+2)*68+m] = a2; As[(kk+3)*68+m] = a3; }
    { int kk = t >> 4, nn = (t & 15) * 4;
      const TI* bp = B + (size_t)(k0 + kk) * 64 + nn;
      Bs[kk*68+nn+0] = ldf(bp+0); Bs[kk*68+nn+1] = ldf(bp+1);
      Bs[kk*68+nn+2] = ldf(bp+2); Bs[kk*68+nn+3] = ldf(bp+3); }
    __syncthreads();
    #pragma unroll
    for (int kk = 0; kk < 16; kk++) {
      float4 a4 = *reinterpret_cast<const float4*>(&As[kk*68 + ty*4]);
      float4 b4 = *reinterpret_cast<const float4*>(&Bs[kk*68 + tx*4]);
      float av[4] = {a4.x,a4.y,a4.z,a4.w}, bv[4] = {b4.x,b4.y,b4.z,b4.w};
      #pragma unroll
      for (int im = 0; im < 4; im++)
        #pragma unroll
        for (int in = 0; in < 4; in++) acc[im][in] += av[im] * bv[in];
    }
    __syncthreads();
  }
  #pragma unroll
  for (int im = 0; im < 4; im++)
    #pragma unroll
    for (int in = 0; in < 4; in++) {
      float v = acc[im][in] + ldf(bias + tx*4 + in);
      int p = m0 + ty*4 + im, h = tx*4 + in;
      if (j < 3) out[(size_t)p * 512 + n*64 + h] = __float2bfloat16(v);
      else       out[(size_t)n * 16384 + (size_t)h * 256 + p] = __float2bfloat16(v);
    }
}

__global__ __launch_bounds__(256) void proj_all(
    const void* __restrict__ x,
    const void* W0, const void* b0, const void* W1, const void* b1,
    const void* W2, const void* b2, const void* W3, const void* b3,
    const void* W4, const void* b4, bf16* __restrict__ tproj)
{
  __shared__ float As[16*68];
  __shared__ float Bs[16*68];
  if (is_bf16_x(x)) {
    const bf16* Ws[5] = {(const bf16*)W0,(const bf16*)W1,(const bf16*)W2,
                         (const bf16*)W3,(const bf16*)W4};
    const bf16* bs[5] = {(const bf16*)b0,(const bf16*)b1,(const bf16*)b2,
                         (const bf16*)b3,(const bf16*)b4};
    proj_body<bf16>((const bf16*)x, Ws, bs, tproj, As, Bs);
  } else {
    const float* Ws[5] = {(const float*)W0,(const float*)W1,(const float*)W2,
                          (const float*)W3,(const float*)W4};
    const float* bs[5] = {(const float*)b0,(const float*)b1,(const float*)b2,
                          (const float*)b3,(const float*)b4};
    proj_body<float>((const float*)x, Ws, bs, tproj, As, Bs);
  }
}

// ---------------- s1t_all: s1t MFMA + tbs (grid y==4) -----------------------
// s1t[r][(i,j)] = sum_{n,k} tc[r][(n,k)] * W_K[n][i][j][k].
template<typename TW>
__device__ __forceinline__ void s1t_body(
    const bf16* __restrict__ tc, const TW* __restrict__ WK,
    bf16* __restrict__ s1t)
{
  const int i = blockIdx.x;
  const int t = threadIdx.x, wid = t >> 6, lane = t & 63, quad = lane >> 4, l16 = lane & 15;
  const int rw = blockIdx.y * 64 + wid * 16;
  floatx4 acc[4];
  #pragma unroll
  for (int jt = 0; jt < 4; jt++) acc[jt] = (floatx4){0.f, 0.f, 0.f, 0.f};
  for (int kc = 0; kc < 16; kc++) {
    short8 af = ld_g8(tc + (size_t)(rw + l16) * 512 + kc*32 + quad*8);
    const int n = kc >> 1, kk = (kc & 1) * 32 + quad * 8;
    #pragma unroll
    for (int jt = 0; jt < 4; jt++) {
      const TW* bp = WK + ((size_t)(n*64 + i) * 64 + jt*16 + l16) * 64 + kk;
      short8 bf;
      if constexpr (sizeof(TW) == 2) {
        bf = ld_g8((const bf16*)bp);
      } else {
        float4 x0 = *reinterpret_cast<const float4*>(bp);
        float4 x1 = *reinterpret_cast<const float4*>(bp + 4);
        bf[0]=bfs(x0.x); bf[1]=bfs(x0.y); bf[2]=bfs(x0.z); bf[3]=bfs(x0.w);
        bf[4]=bfs(x1.x); bf[5]=bfs(x1.y); bf[6]=bfs(x1.z); bf[7]=bfs(x1.w);
      }
      acc[jt] = mfma16(af, bf, acc[jt]);
    }
  }
  #pragma unroll
  for (int jt = 0; jt < 4; jt++)
    #pragma unroll
    for (int reg = 0; reg < 4; reg++)
      s1t[(size_t)(rw + quad*4 + reg) * 4096 + i*64 + jt*16 + l16] =
          __float2bfloat16(acc[jt][reg]);
}

__global__ __launch_bounds__(256) void s1t_all(
    const void* __restrict__ x, const bf16* __restrict__ tb,
    const bf16* __restrict__ tc, const void* __restrict__ WK,
    bf16* __restrict__ tbsbf, bf16* __restrict__ s1t)
{
  if (blockIdx.y == 4) {              // tbs: tbs[q][j] = (1/64)*sum_n tb[q][n][j]
    int t = blockIdx.x * 256 + threadIdx.x;
    int q = t >> 6, j = t & 63;
    float s = 0.f;
    #pragma unroll
    for (int n = 0; n < 8; n++) s += ldf(tb + q*512 + n*64 + j);
    tbsbf[t] = __float2bfloat16(s * 0.015625f);
    return;
  }
  if (is_bf16_x(x)) s1t_body<bf16>(tc, (const bf16*)WK, s1t);
  else              s1t_body<float>(tc, (const float*)WK, s1t);
}

// ---------------- tri_attn (round-12 verbatim) ------------------------------
// LDS 39936 B: [0,34816) c [256][136 B] / Tt [64][528 B]; [34816,39424) Ew
// [16][72 B] x4 waves (per-pt reuse); [39424,39936) scr.
__global__ __launch_bounds__(256) void tri_attn(
    const bf16* __restrict__ ta,     // [p][n*64+h]
    const bf16* __restrict__ tbsbf,  // [q][64]
    const bf16* __restrict__ s1t,    // [r][i*64+j]
    const bf16* __restrict__ tdT,    // [n][h][p]
    const bf16* __restrict__ teT,    // [n][g][q]
    bf16* __restrict__ Sbuf)         // [n][r][h*64+g]
{
  __shared__ __align__(16) char smb[39936];
  const int bx = blockIdx.x;
  const int n = bx & 7;               // n -> XCD affinity
  const int r = 255 - (bx >> 3);      // big-r first
  const int t = threadIdx.x;
  const int wid = t >> 6, lane = t & 63, quad = lane >> 4, l16 = lane & 15;
  bf16* srow = Sbuf + (size_t)n * 1048576 + (size_t)r * 4096;
  if (r < 2) {                        // no valid (p<q<r): S' = 0
    short8 zz = (short8){0,0,0,0,0,0,0,0};
    reinterpret_cast<short8*>(srow)[t]       = zz;
    reinterpret_cast<short8*>(srow)[t + 256] = zz;
    return;
  }
  const int nch  = ((r - 1) >> 5) + 1;   // live 32-q chunks
  const int rcap = nch * 32;             // c rows < rcap are ever read

  // ---- Phase 1: c[q][i] = tbs[q,:]·s1t[r][i,:]
  {
    const bf16* s1r = s1t + (size_t)r * 4096;
    short8 bfr[4][2];
    #pragma unroll
    for (int it = 0; it < 4; it++)
      #pragma unroll
      for (int kc = 0; kc < 2; kc++)
        bfr[it][kc] = ld_g8(s1r + (it*16 + l16)*64 + kc*32 + quad*8);
    #pragma unroll
    for (int qt = 0; qt < 4; qt++) {
      const int q0 = wid * 64 + qt * 16;
      if (q0 >= rcap) continue;          // never read
      if (q0 >= r) {                     // read but fully masked: zero-store
        #pragma unroll
        for (int it = 0; it < 4; it++)
          #pragma unroll
          for (int reg = 0; reg < 4; reg++) {
            int q = q0 + quad*4 + reg;
            *reinterpret_cast<bf16*>(smb + q*136 + (it*16 + l16)*2) =
                __float2bfloat16(0.f);
          }
        continue;
      }
      short8 af0 = ld_g8(tbsbf + (q0 + l16)*64 + quad*8);
      short8 af1 = ld_g8(tbsbf + (q0 + l16)*64 + 32 + quad*8);
      #pragma unroll
      for (int it = 0; it < 4; it++) {
        floatx4 acc = {0.f, 0.f, 0.f, 0.f};
        acc = mfma16(af0, bfr[it][0], acc);
        acc = mfma16(af1, bfr[it][1], acc);
        #pragma unroll
        for (int reg = 0; reg < 4; reg++) {
          int q = q0 + quad*4 + reg;
          float v = (q >= 1 && q < r) ? acc[reg] : 0.f;
          *reinterpret_cast<bf16*>(smb + q*136 + (it*16 + l16)*2) = __float2bfloat16(v);
        }
      }
    }
  }
  short8 taf[4][2];
  #pragma unroll
  for (int pt = 0; pt < 4; pt++)
    #pragma unroll
    for (int kc = 0; kc < 2; kc++)
      taf[pt][kc] = ld_g8(ta + (size_t)((pt*4 + wid)*16 + l16)*512 + n*64
                             + kc*32 + quad*8);
  __syncthreads();                    // c visible

  // ---- Main loop: per-pt E chunk -> immediate T accumulate
  floatx4 Tacc[4][4];
  #pragma unroll
  for (int pt = 0; pt < 4; pt++)
    #pragma unroll
    for (int gt = 0; gt < 4; gt++) Tacc[pt][gt] = (floatx4){0.f, 0.f, 0.f, 0.f};
  float Zp = 0.f;
  char* EwB = smb + 34816 + wid * 1152;          // [16][72 B] bf16 per wave
  for (int ch = 0; ch < nch; ch++) {
    const int qc = ch * 32;
    if (qc + 31 <= wid * 16) continue;  // all this wave's tiles dead
    short8 cfr[2][2];
    #pragma unroll
    for (int qt2 = 0; qt2 < 2; qt2++)
      #pragma unroll
      for (int kc = 0; kc < 2; kc++)
        cfr[qt2][kc] = *reinterpret_cast<const short8*>(
            smb + (qc + qt2*16 + l16)*136 + (kc*32 + quad*8)*2);
    short8 tef[4];                      // prefetch: global latency under E phase
    #pragma unroll
    for (int gt = 0; gt < 4; gt++)
      tef[gt] = ld_g8(teT + (size_t)n*16384 + (gt*16 + l16)*256 + qc + quad*8);
    #pragma unroll
    for (int pt = 0; pt < 4; pt++) {
      const int ptb = (pt*4 + wid) * 16;
      if (ptb >= qc + 31) continue;     // wave-uniform: tile dead
      #pragma unroll
      for (int qt2 = 0; qt2 < 2; qt2++) {
        const int qh = qc + qt2*16;
        char* erow0 = EwB + (quad*4)*72 + (qt2*16 + l16)*2;
        if (qh + 15 <= ptb) {                   // fully-masked half-tile
          #pragma unroll
          for (int reg = 0; reg < 4; reg++)
            *reinterpret_cast<bf16*>(erow0 + reg*72) = __float2bfloat16(0.f);
        } else {
          floatx4 acc = {0.f, 0.f, 0.f, 0.f};
          acc = mfma16(taf[pt][0], cfr[qt2][0], acc);
          acc = mfma16(taf[pt][1], cfr[qt2][1], acc);
          if (qh >= ptb + 16 && qh + 15 < r) {  // interior: no per-lane mask
            #pragma unroll
            for (int reg = 0; reg < 4; reg++) {
              float e = __expf(acc[reg]);
              Zp += e;
              *reinterpret_cast<bf16*>(erow0 + reg*72) = __float2bfloat16(e);
            }
          } else {                              // diagonal / last chunk
            #pragma unroll
            for (int reg = 0; reg < 4; reg++) {
              int p = ptb + quad*4 + reg;
              int q = qh + l16;
              float e = (p < q && q < r) ? __expf(acc[reg]) : 0.f;
              Zp += e;
              *reinterpret_cast<bf16*>(erow0 + reg*72) = __float2bfloat16(e);
            }
          }
        }
      }
      // same-wave DS ops are in-order
      short8 ef = *reinterpret_cast<const short8*>(EwB + l16*72 + quad*16);
      __builtin_amdgcn_s_setprio(1);
      #pragma unroll
      for (int gt = 0; gt < 4; gt++)
        Tacc[pt][gt] = mfma16(ef, tef[gt], Tacc[pt][gt]);
      __builtin_amdgcn_s_setprio(0);
    }
  }
  #pragma unroll
  for (int off = 32; off; off >>= 1) Zp += __shfl_down(Zp, off);
  float* scr = reinterpret_cast<float*>(smb + 39424);
  if (lane == 0) scr[wid] = Zp;
  __syncthreads();                    // closes all c reads; Z visible
  const float rinv = 1.f / (scr[0] + scr[1] + scr[2] + scr[3]);

  // ---- Tt[g][p] (bf16, stride 528 B) over dead c region; skip p >= rcap
  #pragma unroll
  for (int pt = 0; pt < 4; pt++) {
    if ((pt*4 + wid)*16 >= rcap) continue;   // T==0 there, never read
    #pragma unroll
    for (int gt = 0; gt < 4; gt++)
      #pragma unroll
      for (int reg = 0; reg < 4; reg++) {
        int g = gt*16 + l16;
        int p = (pt*4 + wid)*16 + quad*4 + reg;
        *reinterpret_cast<bf16*>(smb + g*528 + p*2) = __float2bfloat16(Tacc[pt][gt][reg]);
      }
  }
  __syncthreads();

  // ---- S[g][h] = T^T·tdT (K capped at 32*nch); store S' = S*rinv
  {
    short8 Taf[8];
    #pragma unroll
    for (int kc = 0; kc < 8; kc++)
      if (kc < nch)
        Taf[kc] = *reinterpret_cast<const short8*>(
            smb + (wid*16 + l16)*528 + (kc*32 + quad*8)*2);
    #pragma unroll
    for (int ht = 0; ht < 4; ht++) {
      floatx4 acc = {0.f, 0.f, 0.f, 0.f};
      __builtin_amdgcn_s_setprio(1);
      #pragma unroll
      for (int kc = 0; kc < 8; kc++) {
        if (kc < nch) {
          short8 bfragd = ld_g8(tdT + (size_t)n*16384 + (ht*16 + l16)*256 + kc*32 + quad*8);
          acc = mfma16(Taf[kc], bfragd, acc);
        }
      }
      __builtin_amdgcn_s_setprio(0);
      #pragma unroll
      for (int reg = 0; reg < 4; reg++) {
        int g = wid*16 + quad*4 + reg, h = ht*16 + l16;
        srow[h*64 + g] = __float2bfloat16(acc[reg] * rinv);
      }
    }
  }
}

// ---------------- z_all: split-K z with internal dtype branch ---------------
template<typename TW>
__device__ __forceinline__ void z_body(
    const bf16* __restrict__ Sbuf, const TW* __restrict__ WV,
    float* __restrict__ zpart, int kslice, char* lds)
{
  const int rt = blockIdx.x, n = blockIdx.y, ks = blockIdx.z;
  const int t = threadIdx.x, wid = t >> 6, lane = t & 63, quad = lane >> 4, l16 = lane & 15;
  const int rw = rt * 64 + wid * 16;
  const int k0 = ks * kslice;
  const TW*  wvn = WV   + (size_t)n * 262144;
  const bf16* sn = Sbuf + (size_t)n * 1048576;
  floatx4 acc[4];
  #pragma unroll
  for (int ft = 0; ft < 4; ft++) acc[ft] = (floatx4){0.f, 0.f, 0.f, 0.f};
  const int row = t >> 3, f8 = (t & 7) * 8;
  for (int kb = k0; kb < k0 + kslice; kb += 32) {
    { const TW* src = wvn + (size_t)(kb + row) * 64 + f8;
      short sv[8];
      if constexpr (sizeof(TW) == 2) {
        short8 v = ld_g8((const bf16*)src);
        #pragma unroll
        for (int j = 0; j < 8; j++) sv[j] = v[j];
      } else {
        float4 a = *reinterpret_cast<const float4*>(src);
        float4 b = *reinterpret_cast<const float4*>(src + 4);
        sv[0]=bfs(a.x); sv[1]=bfs(a.y); sv[2]=bfs(a.z); sv[3]=bfs(a.w);
        sv[4]=bfs(b.x); sv[5]=bfs(b.y); sv[6]=bfs(b.z); sv[7]=bfs(b.w);
      }
      short* dst = reinterpret_cast<short*>(lds + row*136 + f8*2);
      s16x4 lo = {sv[0],sv[1],sv[2],sv[3]}, hi = {sv[4],sv[5],sv[6],sv[7]};
      *reinterpret_cast<s16x4*>(dst)     = lo;
      *reinterpret_cast<s16x4*>(dst + 4) = hi;
    }
    __syncthreads();
    short8 af = ld_g8(sn + (size_t)(rw + l16) * 4096 + kb + quad*8);
    #pragma unroll
    for (int ft = 0; ft < 4; ft++) {
      short8 bfv;
      #pragma unroll
      for (int j = 0; j < 8; j++)
        bfv[j] = *reinterpret_cast<const short*>(
            lds + (quad*8 + j)*136 + (ft*16 + l16)*2);
      acc[ft] = mfma16(af, bfv, acc[ft]);
    }
    __syncthreads();
  }
  float* zp = zpart + (size_t)ks * 131072;
  #pragma unroll
  for (int ft = 0; ft < 4; ft++)
    #pragma unroll
    for (int reg = 0; reg < 4; reg++)
      zp[(size_t)(rw + quad*4 + reg) * 512 + n*64 + ft*16 + l16] = acc[ft][reg];
}

__global__ __launch_bounds__(256) void z_all(
    const void* __restrict__ x, const bf16* __restrict__ Sbuf,
    const void* __restrict__ WV, float* __restrict__ zpart, int kslice)
{
  __shared__ __align__(16) char lds[32 * 136];
  if (is_bf16_x(x)) z_body<bf16>(Sbuf, (const bf16*)WV, zpart, kslice, lds);
  else              z_body<float>(Sbuf, (const float*)WV, zpart, kslice, lds);
}

// zred: zbb[idx] = bf16( sum_ks zpart[ks][idx] ), idx over 256*512.
__global__ __launch_bounds__(256) void zred_kern(
    const float* __restrict__ zpart, bf16* __restrict__ zbb, int ks)
{
  int idx = blockIdx.x * 256 + threadIdx.x;   // 512 blocks
  float s = 0.f;
  for (int k = 0; k < ks; k++) s += zpart[(size_t)k * 131072 + idx];
  zbb[idx] = __float2bfloat16(s);
}

// ---------------- gemm_all: out = zbb @ WO + bO (dtype branch) --------------
template<typename TB, typename TC>
__device__ __forceinline__ void gemm_body(
    const bf16* __restrict__ A, const TB* __restrict__ B, TC* __restrict__ C,
    const TB* __restrict__ bias, float* As, float* Bs)
{
  const int m0 = blockIdx.y * 64, n0 = blockIdx.x * 64;
  const int t = threadIdx.x, tx = t & 15, ty = t >> 4;
  float acc[4][4] = {};
  for (int k0 = 0; k0 < 512; k0 += 16) {
    { int m = t >> 2, kk = (t & 3) * 4;
      const bf16* ap = A + (size_t)(m0 + m) * 512 + (k0 + kk);
      float a0 = ldf(ap+0), a1 = ldf(ap+1), a2 = ldf(ap+2), a3 = ldf(ap+3);
      As[(kk+0)*68+m] = a0; As[(kk+1)*68+m] = a1;
      As[(kk+2)*68+m] = a2; As[(kk+3)*68+m] = a3; }
    { int kk = t >> 4, nn = (t & 15) * 4;
      const TB* bp = B + (size_t)(k0 + kk) * 512 + (n0 + nn);
      Bs[kk*68+nn+0] = ldf(bp+0); Bs[kk*68+nn+1] = ldf(bp+1);
      Bs[kk*68+nn+2] = ldf(bp+2); Bs[kk*68+nn+3] = ldf(bp+3); }
    __syncthreads();
    #pragma unroll
    for (int kk = 0; kk < 16; kk++) {
      float4 a4 = *reinterpret_cast<const float4*>(&As[kk*68 + ty*4]);
      float4 b4 = *reinterpret_cast<const float4*>(&Bs[kk*68 + tx*4]);
      float av[4] = {a4.x,a4.y,a4.z,a4.w}, bv[4] = {b4.x,b4.y,b4.z,b4.w};
      #pragma unroll
      for (int im = 0; im < 4; im++)
        #pragma unroll
        for (int in = 0; in < 4; in++) acc[im][in] += av[im] * bv[in];
    }
    __syncthreads();
  }
  #pragma unroll
  for (int im = 0; im < 4; im++) {
    TC* cp = C + (size_t)(m0 + ty*4 + im) * 512 + n0 + tx*4;
    #pragma unroll
    for (int in = 0; in < 4; in++) {
      float v = acc[im][in] + ldf(bias + n0 + tx*4 + in);
      stf(cp + in, v);
    }
  }
}

__global__ __launch_bounds__(256) void gemm_all(
    const void* __restrict__ x, const bf16* __restrict__ zbb,
    const void* __restrict__ WO, const void* __restrict__ bO,
    void* __restrict__ out)
{
  __shared__ float As[16*68];
  __shared__ float Bs[16*68];
  if (is_bf16_x(x))
    gemm_body<bf16, bf16>(zbb, (const bf16*)WO, (bf16*)out, (const bf16*)bO, As, Bs);
  else
    gemm_body<float, float>(zbb, (const float*)WO, (float*)out, (const float*)bO, As, Bs);
}

extern "C" void kernel_launch(void* const* d_in, const int* in_sizes, int n_in,
                              void* d_out, int out_size, void* d_ws, size_t ws_size,
                              hipStream_t stream)
{
  (void)in_sizes; (void)n_in; (void)out_size;
  // Workspace (round-12 layout):
  //   tproj bf16 [256, 1310976); tbsbf [1310976, 1343744)
  //   s1t bf16 [1343744, 3440896); zbb bf16 [3440896, 3703040)
  //   Sbuf bf16 [4194304, 20971520)
  //   zpart fp32: ks=8 @ [20971520, 25165824) if ws allows, else ks=2 over
  //   dead s1t region [1343744, ...) (s1t dead after tri_attn).
  char* wsb = (char*)d_ws;
  bf16* tproj = (bf16*)(wsb + 256);
  bf16* tbsbf = (bf16*)(wsb + 1310976);
  bf16* s1t   = (bf16*)(wsb + 1343744);
  bf16* zbb   = (bf16*)(wsb + 3440896);
  bf16* Sbuf  = (bf16*)(wsb + 4194304);
  const long TE = 131072;
  const bool bigws = (ws_size == 0) || (ws_size >= 25165824);
  const int  ks     = bigws ? 8 : 2;
  const int  kslice = 4096 / ks;
  float* zpart = (float*)(bigws ? (wsb + 20971520) : (wsb + 1343744));

  proj_all<<<dim3(1,4,40), 256, 0, stream>>>(
      d_in[0], d_in[1], d_in[2], d_in[3], d_in[4], d_in[5], d_in[6],
      d_in[7], d_in[8], d_in[9], d_in[10], tproj);
  s1t_all<<<dim3(64,5), 256, 0, stream>>>(
      d_in[0], tproj + 1*TE, tproj + 2*TE, d_in[12], tbsbf, s1t);
  tri_attn<<<2048, 256, 0, stream>>>(
      tproj, tbsbf, s1t, tproj + 3*TE, tproj + 4*TE, Sbuf);
  z_all<<<dim3(4,8,ks), 256, 0, stream>>>(
      d_in[0], Sbuf, d_in[11], zpart, kslice);
  zred_kern<<<512, 256, 0, stream>>>(zpart, zbb, ks);
  gemm_all<<<dim3(8,4), 256, 0, stream>>>(
      d_in[0], zbb, d_in[13], d_in[14], d_out);
}